// Round 1
// baseline (286.193 us; speedup 1.0000x reference)
//
#include <hip/hip_runtime.h>
#include <hip/hip_bf16.h>

// EdgePredictor: out[e] = relu(concat(X[row], X[col]) @ W1 + b1) @ W2 + b2
// Key transform: first layer is linear in the concat, so precompute per-node
//   A[n] = X[n] @ W1[0:128, :]   (128 outs)
//   B[n] = X[n] @ W1[128:256, :] (128 outs)
// stored bf16 in d_ws as AB[n][256] = {A[n] | B[n]}.
// Then per edge: out = relu(A[row] + B[col] + b1) @ W2 + b2.

#define EMBED 128

// --- Kernel 0: detect whether edge_index is int64 (high words all zero) or int32.
__global__ void detect_idx_mode(const int* __restrict__ idx, int* __restrict__ flag) {
    if (threadIdx.x == 0 && blockIdx.x == 0) {
        int allz = 1;
        for (int i = 0; i < 64; ++i) {
            if (idx[2 * i + 1] != 0) { allz = 0; break; }
        }
        *flag = allz;  // 1 => int64 layout, 0 => int32 layout
    }
}

// --- Kernel 1: precompute AB table. Block = 256 threads, 16 nodes per block.
// Thread t: half = t>>7 (0 => A, 1 => B), j = t&127 (output column).
// acc[m] for 16 nodes; X tile staged in LDS k-major for broadcast reads.
__global__ __launch_bounds__(256) void precompute_ab(
    const float* __restrict__ X, const float* __restrict__ W1,
    __hip_bfloat16* __restrict__ AB, int n_nodes) {
    __shared__ float xs[128][16];  // [k][m], 8 KB

    const int t = threadIdx.x;
    const int node_base = blockIdx.x * 16;

    // Stage X tile: thread t loads 8 consecutive k for node m = t>>4.
    {
        const int m  = t >> 4;
        const int kb = (t & 15) * 8;
        const int node = node_base + m;
        float4 x0 = make_float4(0.f, 0.f, 0.f, 0.f);
        float4 x1 = make_float4(0.f, 0.f, 0.f, 0.f);
        if (node < n_nodes) {
            const float* xp = X + (size_t)node * EMBED + kb;
            x0 = *(const float4*)xp;
            x1 = *(const float4*)(xp + 4);
        }
        xs[kb + 0][m] = x0.x; xs[kb + 1][m] = x0.y;
        xs[kb + 2][m] = x0.z; xs[kb + 3][m] = x0.w;
        xs[kb + 4][m] = x1.x; xs[kb + 5][m] = x1.y;
        xs[kb + 6][m] = x1.z; xs[kb + 7][m] = x1.w;
    }
    __syncthreads();

    const int j    = t & 127;
    const int half = t >> 7;
    const float* wp = W1 + (size_t)half * EMBED * EMBED + j;  // W1[half*128 + k][j]

    float acc[16];
#pragma unroll
    for (int i = 0; i < 16; ++i) acc[i] = 0.f;

#pragma unroll 8
    for (int k = 0; k < 128; ++k) {
        const float w = wp[(size_t)k * EMBED];
        const float4 xa = *(const float4*)&xs[k][0];
        const float4 xb = *(const float4*)&xs[k][4];
        const float4 xc = *(const float4*)&xs[k][8];
        const float4 xd = *(const float4*)&xs[k][12];
        acc[0]  += w * xa.x;  acc[1]  += w * xa.y;
        acc[2]  += w * xa.z;  acc[3]  += w * xa.w;
        acc[4]  += w * xb.x;  acc[5]  += w * xb.y;
        acc[6]  += w * xb.z;  acc[7]  += w * xb.w;
        acc[8]  += w * xc.x;  acc[9]  += w * xc.y;
        acc[10] += w * xc.z;  acc[11] += w * xc.w;
        acc[12] += w * xd.x;  acc[13] += w * xd.y;
        acc[14] += w * xd.z;  acc[15] += w * xd.w;
    }

#pragma unroll
    for (int m = 0; m < 16; ++m) {
        const int node = node_base + m;
        if (node < n_nodes)
            AB[(size_t)node * 256 + t] = __float2bfloat16(acc[m]);
    }
}

// --- Kernel 2: per-edge MLP. One wave per edge; lane l handles dims 2l, 2l+1.
__global__ __launch_bounds__(256) void edge_mlp(
    const __hip_bfloat16* __restrict__ AB,
    const int* __restrict__ eidx, const int* __restrict__ flag,
    const float* __restrict__ b1, const float* __restrict__ W2,
    const float* __restrict__ b2, float* __restrict__ out, int n_edges) {
    const int lane = threadIdx.x & 63;
    const int e = blockIdx.x * 4 + (threadIdx.x >> 6);
    if (e >= n_edges) return;

    const int mode = *flag;  // wave-uniform
    int row, col;
    if (mode) {  // int64 layout: value at int32 index 2*k, high word at 2*k+1
        row = eidx[2 * (size_t)e];
        col = eidx[2 * ((size_t)n_edges + e)];
    } else {     // int32 layout
        row = eidx[e];
        col = eidx[n_edges + e];
    }

    const __hip_bfloat162* ap = (const __hip_bfloat162*)(AB + (size_t)row * 256);
    const __hip_bfloat162* bp = (const __hip_bfloat162*)(AB + (size_t)col * 256 + 128);
    const __hip_bfloat162 av = ap[lane];
    const __hip_bfloat162 bv = bp[lane];
    const float2 bias = *(const float2*)(b1 + 2 * lane);

    float h0 = __bfloat162float(av.x) + __bfloat162float(bv.x) + bias.x;
    float h1 = __bfloat162float(av.y) + __bfloat162float(bv.y) + bias.y;
    h0 = fmaxf(h0, 0.f);
    h1 = fmaxf(h1, 0.f);

    // W2 row-major (128,2): float4 at 4*lane = {W2[2l][0], W2[2l][1], W2[2l+1][0], W2[2l+1][1]}
    const float4 w = *(const float4*)(W2 + 4 * lane);
    float c0 = h0 * w.x + h1 * w.z;
    float c1 = h0 * w.y + h1 * w.w;

#pragma unroll
    for (int off = 32; off > 0; off >>= 1) {
        c0 += __shfl_down(c0, off, 64);
        c1 += __shfl_down(c1, off, 64);
    }
    if (lane == 0) {
        float2 o;
        o.x = c0 + b2[0];
        o.y = c1 + b2[1];
        *(float2*)(out + (size_t)e * 2) = o;
    }
}

extern "C" void kernel_launch(void* const* d_in, const int* in_sizes, int n_in,
                              void* d_out, int out_size, void* d_ws, size_t ws_size,
                              hipStream_t stream) {
    const float* X   = (const float*)d_in[0];
    const int*   idx = (const int*)d_in[1];
    const float* W1  = (const float*)d_in[2];
    const float* b1  = (const float*)d_in[3];
    const float* W2  = (const float*)d_in[4];
    const float* b2  = (const float*)d_in[5];
    float* out = (float*)d_out;

    const int n_nodes = in_sizes[0] / EMBED;   // 100000
    const int n_edges = in_sizes[1] / 2;       // 500000

    int* flag = (int*)d_ws;
    __hip_bfloat16* AB = (__hip_bfloat16*)((char*)d_ws + 256);
    // AB needs n_nodes*256*2 bytes = 51.2 MB; flag lives in the first 256 B.

    detect_idx_mode<<<1, 64, 0, stream>>>(idx, flag);
    precompute_ab<<<(n_nodes + 15) / 16, 256, 0, stream>>>(X, W1, AB, n_nodes);
    edge_mlp<<<(n_edges + 3) / 4, 256, 0, stream>>>(AB, idx, flag, b1, W2, b2, out, n_edges);
}

// Round 2
// 203.138 us; speedup vs baseline: 1.4089x; 1.4089x over previous
//
#include <hip/hip_runtime.h>
#include <hip/hip_bf16.h>

// EdgePredictor: out[e] = relu(concat(X[row], X[col]) @ W1 + b1) @ W2 + b2
// First layer is linear in the concat, so precompute per-node
//   A[n] = X[n] @ W1[0:128, :],  B[n] = X[n] @ W1[128:256, :]
// stored bf16 in d_ws as AB[n][256] = {A[n] | B[n]}.
// Per edge: out = relu(A[row] + B[col] + b1) @ W2 + b2.
//
// R2: precompute via f16 MFMA (was fp32 VALU, 130us, VALUBusy 39%, 6M LDS
// bank conflicts); edge phase batched 16 edges/wave (was 1 edge/wave,
// latency-bound, 500K waves).

#define EMBED 128

typedef _Float16 half8 __attribute__((ext_vector_type(8)));
typedef float floatx4 __attribute__((ext_vector_type(4)));

// --- Kernel 0: detect whether edge_index is int64 (high words all zero) or int32.
__global__ void detect_idx_mode(const int* __restrict__ idx, int* __restrict__ flag) {
    if (threadIdx.x == 0 && blockIdx.x == 0) {
        int allz = 1;
        for (int i = 0; i < 64; ++i) {
            if (idx[2 * i + 1] != 0) { allz = 0; break; }
        }
        *flag = allz;  // 1 => int64 layout, 0 => int32 layout
    }
}

// --- Kernel 1: transpose+convert W1 (256x128 fp32) -> W_T (256x128 f16),
// where W_T[j][k] = Wcat[k][j], Wcat[k][j<128]=W1[k][j], Wcat[k][j>=128]=W1[128+k][j-128].
// Grid: 16 r-tiles x 8 c-tiles = 128 blocks, 256 threads (16x16).
__global__ __launch_bounds__(256) void wtrans(
    const float* __restrict__ W1, _Float16* __restrict__ WT) {
    __shared__ float lds[16][17];
    const int ty = threadIdx.x >> 4, tx = threadIdx.x & 15;
    const int r0 = (blockIdx.x >> 3) * 16;   // 0..240, source row tile (k-ish)
    const int c0 = (blockIdx.x & 7) * 16;    // 0..112, source col tile
    lds[ty][tx] = W1[(r0 + ty) * 128 + c0 + tx];
    __syncthreads();
    const int jbase = c0 + (r0 >= 128 ? 128 : 0);
    const int kbase = r0 & 127;
    WT[(size_t)(jbase + ty) * 128 + kbase + tx] = (_Float16)lds[tx][ty];
}

// --- Kernel 2: AB = [X | X] @ Wcat via f16 MFMA. M-tile 64/block, 4 waves,
// wave w covers cols [w*64, w*64+64). K=128 (4 MFMA steps), no LDS.
__global__ __launch_bounds__(256) void gemm_ab(
    const float* __restrict__ X, const _Float16* __restrict__ WT,
    __hip_bfloat16* __restrict__ AB, int n_nodes) {
    const int w    = threadIdx.x >> 6;
    const int lane = threadIdx.x & 63;
    const int lm   = lane & 15;
    const int quad = lane >> 4;
    const int mblk = blockIdx.x * 64;

    floatx4 acc[4][4];  // [mf][nf]
#pragma unroll
    for (int a = 0; a < 4; ++a)
#pragma unroll
        for (int b = 0; b < 4; ++b)
            acc[a][b] = (floatx4){0.f, 0.f, 0.f, 0.f};

#pragma unroll
    for (int ks = 0; ks < 4; ++ks) {
        const int k0 = ks * 32 + quad * 8;
        // A-frags: A[m = lane&15][k = quad*8+j] from X (fp32 -> f16).
        half8 af[4];
#pragma unroll
        for (int mf = 0; mf < 4; ++mf) {
            int m = mblk + mf * 16 + lm;
            if (m > n_nodes - 1) m = n_nodes - 1;  // clamp; padded rows never stored
            const float* xp = X + (size_t)m * EMBED + k0;
            const float4 x0 = *(const float4*)xp;
            const float4 x1 = *(const float4*)(xp + 4);
            half8 a;
            a[0] = (_Float16)x0.x; a[1] = (_Float16)x0.y;
            a[2] = (_Float16)x0.z; a[3] = (_Float16)x0.w;
            a[4] = (_Float16)x1.x; a[5] = (_Float16)x1.y;
            a[6] = (_Float16)x1.z; a[7] = (_Float16)x1.w;
            af[mf] = a;
        }
        // B-frags: B[k = quad*8+j][n = lane&15] = WT[n][k..k+8], contiguous 16B.
#pragma unroll
        for (int nf = 0; nf < 4; ++nf) {
            const int n = w * 64 + nf * 16 + lm;
            const half8 bf = *(const half8*)(WT + (size_t)n * 128 + k0);
#pragma unroll
            for (int mf = 0; mf < 4; ++mf)
                acc[mf][nf] = __builtin_amdgcn_mfma_f32_16x16x32_f16(af[mf], bf, acc[mf][nf], 0, 0, 0);
        }
    }

    // Store: D col = lane&15, row = quad*4 + reg.
#pragma unroll
    for (int mf = 0; mf < 4; ++mf) {
#pragma unroll
        for (int r = 0; r < 4; ++r) {
            const int node = mblk + mf * 16 + quad * 4 + r;
            if (node < n_nodes) {
                __hip_bfloat16* rowp = AB + (size_t)node * 256 + w * 64 + lm;
#pragma unroll
                for (int nf = 0; nf < 4; ++nf)
                    rowp[nf * 16] = __float2bfloat16(acc[mf][nf][r]);
            }
        }
    }
}

// --- Kernel 3: per-edge MLP, 16 edges per wave.
__global__ __launch_bounds__(256) void edge_mlp(
    const __hip_bfloat162* __restrict__ AB2,
    const int* __restrict__ eidx, const int* __restrict__ flag,
    const float* __restrict__ b1, const float* __restrict__ W2,
    const float* __restrict__ b2, float* __restrict__ out, int n_edges) {
    const int lane  = threadIdx.x & 63;
    const int ebase = (blockIdx.x * 4 + (threadIdx.x >> 6)) * 16;
    if (ebase >= n_edges) return;  // n_edges % 16 == 0, so full 16 when active

    const int mode = *flag;  // wave-uniform
    int rows[16], cols[16];
    if (mode) {  // int64 layout: low word at int32 index 2*k
#pragma unroll
        for (int i = 0; i < 16; ++i) {
            rows[i] = eidx[2 * (size_t)(ebase + i)];
            cols[i] = eidx[2 * ((size_t)n_edges + ebase + i)];
        }
    } else {
#pragma unroll
        for (int i = 0; i < 16; ++i) {
            rows[i] = eidx[ebase + i];
            cols[i] = eidx[n_edges + ebase + i];
        }
    }

    // Gather: per edge, A-half row (64 lanes x 4B = 256B) and B-half row.
    __hip_bfloat162 av[16], bv[16];
#pragma unroll
    for (int i = 0; i < 16; ++i) av[i] = AB2[(size_t)rows[i] * 128 + lane];
#pragma unroll
    for (int i = 0; i < 16; ++i) bv[i] = AB2[(size_t)cols[i] * 128 + 64 + lane];

    const float2 bias = *(const float2*)(b1 + 2 * lane);
    const float4 wv   = *(const float4*)(W2 + 4 * lane);  // W2[2l][0..1], W2[2l+1][0..1]
    const float  o0   = b2[0], o1 = b2[1];

    float r0 = 0.f, r1 = 0.f;
#pragma unroll
    for (int i = 0; i < 16; ++i) {
        float h0 = fmaxf(__bfloat162float(av[i].x) + __bfloat162float(bv[i].x) + bias.x, 0.f);
        float h1 = fmaxf(__bfloat162float(av[i].y) + __bfloat162float(bv[i].y) + bias.y, 0.f);
        float c0 = h0 * wv.x + h1 * wv.z;
        float c1 = h0 * wv.y + h1 * wv.w;
#pragma unroll
        for (int off = 32; off > 0; off >>= 1) {
            c0 += __shfl_xor(c0, off, 64);
            c1 += __shfl_xor(c1, off, 64);
        }
        if (lane == i) { r0 = c0; r1 = c1; }  // lane i keeps edge i's result
    }
    if (lane < 16) {
        float2 o;
        o.x = r0 + o0;
        o.y = r1 + o1;
        *(float2*)(out + (size_t)(ebase + lane) * 2) = o;
    }
}

extern "C" void kernel_launch(void* const* d_in, const int* in_sizes, int n_in,
                              void* d_out, int out_size, void* d_ws, size_t ws_size,
                              hipStream_t stream) {
    const float* X   = (const float*)d_in[0];
    const int*   idx = (const int*)d_in[1];
    const float* W1  = (const float*)d_in[2];
    const float* b1  = (const float*)d_in[3];
    const float* W2  = (const float*)d_in[4];
    const float* b2  = (const float*)d_in[5];
    float* out = (float*)d_out;

    const int n_nodes = in_sizes[0] / EMBED;   // 100000
    const int n_edges = in_sizes[1] / 2;       // 500000

    // ws layout: flag @0 (4B), AB @256 (n_nodes*256*2 = 51.2MB), WT after AB (64KB).
    int* flag = (int*)d_ws;
    __hip_bfloat16* AB = (__hip_bfloat16*)((char*)d_ws + 256);
    _Float16* WT = (_Float16*)((char*)d_ws + 256 + (size_t)n_nodes * 256 * 2);

    detect_idx_mode<<<1, 64, 0, stream>>>(idx, flag);
    wtrans<<<128, 256, 0, stream>>>(W1, WT);
    gemm_ab<<<(n_nodes + 63) / 64, 256, 0, stream>>>(X, WT, AB, n_nodes);
    edge_mlp<<<(n_edges + 63) / 64, 256, 0, stream>>>(
        (const __hip_bfloat162*)AB, idx, flag, b1, W2, b2, out, n_edges);
}

// Round 3
// 163.658 us; speedup vs baseline: 1.7487x; 1.2412x over previous
//
#include <hip/hip_runtime.h>
#include <hip/hip_bf16.h>

// EdgePredictor: out[e] = relu(concat(X[row], X[col]) @ W1 + b1) @ W2 + b2
// Precompute per-node AB[n][256] = {X[n]@W1[:128,:] | X[n]@W1[128:,:]} in f16.
// Per edge: out = relu(A[row] + B[col] + b1) @ W2 + b2.
//
// R3: edge phase uses MFMA for the W2 dot (was 192 shuffle/DS ops per wave —
// DS-pipe bound at 74.7us, VALUBusy 33%, HBM 21%). gemm_ab stages X-tile in
// LDS as f16 once per block (was 4x-redundant strided global A-frag loads +
// per-wave cvt). AB stored f16 (packed-f16 edge math, better precision).
// prep kernels fused; detect is now a 64-lane ballot (was 1-thread serial).

#define EMBED 128

typedef _Float16 half8 __attribute__((ext_vector_type(8)));
typedef _Float16 half4 __attribute__((ext_vector_type(4)));
typedef float floatx4 __attribute__((ext_vector_type(4)));

// --- Kernel 0: fused prep.
// Blocks 0..127: transpose+convert W1 (256x128 f32) -> WT (256x128 f16),
//   WT[j][k] = Wcat[k][j] (Wcat = [W1 top | W1 bottom] per concat split).
// Block 128: idx-mode ballot detect; W2PT[16][128] f16 (W2 padded+transposed);
//   b1f[128] f16.
__global__ __launch_bounds__(256) void prep(
    const float* __restrict__ W1, const float* __restrict__ W2,
    const float* __restrict__ b1, const int* __restrict__ idx,
    _Float16* __restrict__ WT, _Float16* __restrict__ W2PT,
    _Float16* __restrict__ b1f, int* __restrict__ flag) {
    if (blockIdx.x < 128) {
        __shared__ float lds[16][17];
        const int ty = threadIdx.x >> 4, tx = threadIdx.x & 15;
        const int r0 = (blockIdx.x >> 3) * 16;   // source W1 row tile
        const int c0 = (blockIdx.x & 7) * 16;    // source W1 col tile
        lds[ty][tx] = W1[(r0 + ty) * 128 + c0 + tx];
        __syncthreads();
        const int jbase = c0 + (r0 >= 128 ? 128 : 0);
        const int kbase = r0 & 127;
        WT[(size_t)(jbase + ty) * 128 + kbase + tx] = (_Float16)lds[tx][ty];
    } else {
        const int t = threadIdx.x;
        if (t < 64) {  // int64 layout iff first 64 high words are all zero
            const int hw = idx[2 * t + 1];
            const unsigned long long m = __ballot(hw != 0);
            if (t == 0) *flag = (m == 0ull) ? 1 : 0;
        }
        if (t < 128) b1f[t] = (_Float16)b1[t];
        for (int i = t; i < 2048; i += 256) {  // W2PT[n][k] = n<2 ? W2[k][n] : 0
            const int n = i >> 7, k = i & 127;
            W2PT[i] = (n < 2) ? (_Float16)W2[k * 2 + n] : (_Float16)0.f;
        }
    }
}

// --- Kernel 1: AB = [X | X] @ Wcat via f16 MFMA. M-tile 64 nodes/block,
// 4 waves, wave w covers output cols [w*64, w*64+64). X-tile staged in LDS
// as f16, row stride 136 (2-way bank aliasing only).
__global__ __launch_bounds__(256) void gemm_ab(
    const float* __restrict__ X, const _Float16* __restrict__ WT,
    _Float16* __restrict__ AB, int n_nodes) {
    __shared__ _Float16 xs[64 * 136];  // 17408 B
    const int t = threadIdx.x;
    const int mblk = blockIdx.x * 64;

    // Stage: 64 rows x 128 f32, coalesced float4 loads, convert once.
#pragma unroll
    for (int i = 0; i < 8; ++i) {
        const int flat = i * 1024 + t * 4;  // float index in 64x128 tile
        const int row = flat >> 7, col = flat & 127;
        int node = mblk + row;
        if (node > n_nodes - 1) node = n_nodes - 1;  // clamp; never stored
        const float4 v = *(const float4*)(X + (size_t)node * EMBED + col);
        half4 h;
        h[0] = (_Float16)v.x; h[1] = (_Float16)v.y;
        h[2] = (_Float16)v.z; h[3] = (_Float16)v.w;
        *(half4*)(xs + row * 136 + col) = h;
    }
    __syncthreads();

    const int w = t >> 6, lane = t & 63, lm = lane & 15, quad = lane >> 4;

    floatx4 acc[4][4];
#pragma unroll
    for (int a = 0; a < 4; ++a)
#pragma unroll
        for (int b = 0; b < 4; ++b)
            acc[a][b] = (floatx4){0.f, 0.f, 0.f, 0.f};

#pragma unroll
    for (int ks = 0; ks < 4; ++ks) {
        const int k0 = ks * 32 + quad * 8;
        half8 af[4];
#pragma unroll
        for (int mf = 0; mf < 4; ++mf)
            af[mf] = *(const half8*)(xs + (mf * 16 + lm) * 136 + k0);
#pragma unroll
        for (int nf = 0; nf < 4; ++nf) {
            const int n = w * 64 + nf * 16 + lm;
            const half8 bf = *(const half8*)(WT + (size_t)n * EMBED + k0);
#pragma unroll
            for (int mf = 0; mf < 4; ++mf)
                acc[mf][nf] = __builtin_amdgcn_mfma_f32_16x16x32_f16(af[mf], bf, acc[mf][nf], 0, 0, 0);
        }
    }

    // D: col = lane&15 (output col j), row = quad*4+reg (node).
#pragma unroll
    for (int mf = 0; mf < 4; ++mf) {
#pragma unroll
        for (int r = 0; r < 4; ++r) {
            const int node = mblk + mf * 16 + quad * 4 + r;
            if (node < n_nodes) {
                _Float16* rowp = AB + (size_t)node * 256 + w * 64 + lm;
#pragma unroll
                for (int nf = 0; nf < 4; ++nf)
                    rowp[nf * 16] = (_Float16)acc[mf][nf][r];
            }
        }
    }
}

// --- Kernel 2: per-edge MLP, 16 edges/wave, W2 dot via one MFMA chain.
// Lane l serves edge ebase+(l&15); gathers land directly in MFMA A-layout
// (A[m=lane&15][k=quad*8+j]). D[row=quad*4+r][col=lane&15] -> edge, class.
__global__ __launch_bounds__(256) void edge_mlp(
    const _Float16* __restrict__ AB, const int* __restrict__ eidx,
    const int* __restrict__ flag, const _Float16* __restrict__ b1f,
    const _Float16* __restrict__ W2PT, const float* __restrict__ b2,
    float* __restrict__ out, int n_edges) {
    const int lane = threadIdx.x & 63, lm = lane & 15, quad = lane >> 4;
    const int ebase = (blockIdx.x * 4 + (threadIdx.x >> 6)) * 16;
    if (ebase >= n_edges) return;

    const int mode = *flag;  // wave-uniform
    int e = ebase + lm;
    if (e > n_edges - 1) e = n_edges - 1;  // tail clamp; stores guarded
    int row, col;
    if (mode) {  // int64 layout: low word at int32 index 2*k
        row = eidx[2 * (size_t)e];
        col = eidx[2 * ((size_t)n_edges + e)];
    } else {
        row = eidx[e];
        col = eidx[(size_t)n_edges + e];
    }

    const _Float16* ap = AB + (size_t)row * 256;        // A-half
    const _Float16* bp = AB + (size_t)col * 256 + 128;  // B-half

    floatx4 acc = (floatx4){0.f, 0.f, 0.f, 0.f};
#pragma unroll
    for (int ks = 0; ks < 4; ++ks) {
        const int k0 = ks * 32 + quad * 8;
        const half8 a  = *(const half8*)(ap + k0);
        const half8 b  = *(const half8*)(bp + k0);
        const half8 bi = *(const half8*)(b1f + k0);
        half8 h = a + b + bi;
#pragma unroll
        for (int j = 0; j < 8; ++j)
            h[j] = h[j] > (_Float16)0.f ? h[j] : (_Float16)0.f;
        const half8 wv = *(const half8*)(W2PT + lm * 128 + k0);
        acc = __builtin_amdgcn_mfma_f32_16x16x32_f16(h, wv, acc, 0, 0, 0);
    }

    if (lm < 2) {
        const float b2v = b2[lm];
#pragma unroll
        for (int r = 0; r < 4; ++r) {
            const int ed = ebase + quad * 4 + r;
            if (ed < n_edges)
                out[(size_t)ed * 2 + lm] = acc[r] + b2v;
        }
    }
}

extern "C" void kernel_launch(void* const* d_in, const int* in_sizes, int n_in,
                              void* d_out, int out_size, void* d_ws, size_t ws_size,
                              hipStream_t stream) {
    const float* X   = (const float*)d_in[0];
    const int*   idx = (const int*)d_in[1];
    const float* W1  = (const float*)d_in[2];
    const float* b1  = (const float*)d_in[3];
    const float* W2  = (const float*)d_in[4];
    const float* b2  = (const float*)d_in[5];
    float* out = (float*)d_out;

    const int n_nodes = in_sizes[0] / EMBED;   // 100000
    const int n_edges = in_sizes[1] / 2;       // 500000

    // ws: flag @0 | AB @256 (n_nodes*256*2 B) | WT (64KB) | W2PT (4KB) | b1f (256B)
    char* ws = (char*)d_ws;
    int*      flag = (int*)ws;
    _Float16* AB   = (_Float16*)(ws + 256);
    _Float16* WT   = (_Float16*)(ws + 256 + (size_t)n_nodes * 512);
    _Float16* W2PT = WT + 256 * 128;
    _Float16* b1f  = W2PT + 16 * 128;

    prep<<<129, 256, 0, stream>>>(W1, W2, b1, idx, WT, W2PT, b1f, flag);
    gemm_ab<<<(n_nodes + 63) / 64, 256, 0, stream>>>(X, WT, AB, n_nodes);
    edge_mlp<<<(n_edges + 63) / 64, 256, 0, stream>>>(
        AB, idx, flag, b1f, W2PT, b2, out, n_edges);
}